// Round 9
// baseline (321.961 us; speedup 1.0000x reference)
//
#include <hip/hip_runtime.h>
#include <hip/hip_bf16.h>
#include <math.h>

#define CCLS 16
#define BB   2048

using bf16x8 = __attribute__((ext_vector_type(8))) short;
using short8 = __attribute__((ext_vector_type(8))) short;
using f32x4  = __attribute__((ext_vector_type(4))) float;

// fp32 -> (hi, lo) bf16 split (RNE; hi+lo reproduces ~24 mantissa bits)
__device__ __forceinline__ void split2(float e, short& hi, short& lo) {
    __hip_bfloat16 h = __float2bfloat16(e);
    hi = __builtin_bit_cast(short, h);
    lo = __builtin_bit_cast(short, __float2bfloat16(e - __bfloat162float(h)));
}

// LDS-visibility barrier that does NOT drain vmcnt.
__device__ __forceinline__ void soft_barrier() {
    asm volatile("s_waitcnt lgkmcnt(0)" ::: "memory");
    __builtin_amdgcn_s_barrier();
    asm volatile("" ::: "memory");
}

// global -> LDS direct copy, 16B/lane; lds dest is wave-uniform base
__device__ __forceinline__ void gll16(const void* g, void* l) {
    __builtin_amdgcn_global_load_lds(
        (const __attribute__((address_space(1))) unsigned*)g,
        (__attribute__((address_space(3))) unsigned*)l, 16, 0, 0);
}

// Fragment-major layout for a 128-row x 32-k bf16 tile (8 KB/plane):
//   L(row, kchunk) = (row>>4)<<10 | kchunk<<8 | (row&15)<<4   (kchunk = k/8)

// ---------------------------------------------------------------------------
// One-time pack: x and W1..W5 -> [hi 8KB][lo 8KB] fragment-major 128x32 tiles.
// ---------------------------------------------------------------------------
struct PackDesc {
    const float* src[6];
    int nrt[6];
    int ksn[6];
    int kreal[6];
    int beg[7];
};

__global__ __launch_bounds__(256)
void pack_kernel(PackDesc d, char* __restrict__ base)
{
    const int bid = blockIdx.x;
    int s = 0;
    #pragma unroll
    for (int i = 0; i < 5; ++i) s += (bid >= d.beg[i + 1]);
    const int t    = bid - d.beg[s];
    const int ksn  = d.ksn[s], nrt = d.nrt[s], kreal = d.kreal[s];
    const int perc = nrt * ksn;
    const int c  = t / perc;
    const int r  = t - c * perc;
    const int rt = r / ksn;
    const int ks = r - rt * ksn;
    const float* src = d.src[s] + ((size_t)(c * nrt + rt) * 128) * kreal;
    char* dst = base + (size_t)bid * 16384;
    const int tid = threadIdx.x;

    #pragma unroll
    for (int it = 0; it < 2; ++it) {
        const int row = (tid >> 2) + (it << 6);
        const int cc  = tid & 3;
        const int q   = ((row >> 4) << 10) | (cc << 8) | ((row & 15) << 4);
        const int k0  = ks * 32 + cc * 8;
        const float* sp = src + (size_t)row * kreal + k0;
        float e[8];
        if (k0 + 8 <= kreal) {
            float4 v0 = *(const float4*)sp;
            float4 v1 = *(const float4*)(sp + 4);
            e[0]=v0.x; e[1]=v0.y; e[2]=v0.z; e[3]=v0.w;
            e[4]=v1.x; e[5]=v1.y; e[6]=v1.z; e[7]=v1.w;
        } else {
            #pragma unroll
            for (int j = 0; j < 8; ++j) e[j] = (k0 + j < kreal) ? sp[j] : 0.f;
        }
        short hv[8], lv[8];
        #pragma unroll
        for (int j = 0; j < 8; ++j) split2(e[j], hv[j], lv[j]);
        *(short8*)(dst + q)        = (short8){hv[0],hv[1],hv[2],hv[3],hv[4],hv[5],hv[6],hv[7]};
        *(short8*)(dst + 8192 + q) = (short8){lv[0],lv[1],lv[2],lv[3],lv[4],lv[5],lv[6],lv[7]};
    }
}

// ---------------------------------------------------------------------------
// MFMA GEMM (R8 structure), plus ablation variants for diagnostics:
//   ABL 0 = full; 1 = no-convert (bit-cast staging, same ds_writes);
//   2 = no in-loop A global loads (stale regs through same cvt VALU);
//   5 = no staging at all (ds_read+MFMA+barrier skeleton).  REP repeats the
//   whole K loop (incl. per-rep prologue) for top-5 rocprof visibility.
// ---------------------------------------------------------------------------
template<int BM, int K, bool PREPACK, bool FUSE_BN, bool WRITE_STATS,
         int ABL = 0, int REP = 1>
__global__ __launch_bounds__(256, 2)
void gemm8_kernel(const float* __restrict__ A, const char* __restrict__ Apk,
                  const char* __restrict__ Wpk, const float* __restrict__ bias,
                  const float* __restrict__ psumIn, const float* __restrict__ psqIn,
                  const float* __restrict__ gIn, const float* __restrict__ beIn,
                  float* __restrict__ Out,
                  float* __restrict__ psumOut, float* __restrict__ psqOut,
                  const int Fout, const int nbtIn)
{
    constexpr int KS    = (K + 31) / 32;
    constexpr int PLANE = BM * 64;
    constexpr int BUFSZ = PREPACK ? 32768 : 2 * PLANE;
    static_assert(PREPACK || (K % 32 == 0), "non-prepack K must be mult of 32");
    static_assert(PREPACK || (KS % 2 == 0) || (KS == 1), "ping-pong needs even KS");

    __shared__ __align__(16) char sm[2 * BUFSZ + (FUSE_BN ? 8 * K : 16)];
    float* scs = (float*)(sm + 2 * BUFSZ);
    float* shs = scs + (FUSE_BN ? K : 0);

    const int tid   = threadIdx.x;
    const int btile = blockIdx.x, otile = blockIdx.y, c = blockIdx.z;

    if (FUSE_BN) {
        for (int f = tid; f < K; f += 256) {
            const float* ps = psumIn + ((size_t)c * K + f) * nbtIn;
            const float* pq = psqIn  + ((size_t)c * K + f) * nbtIn;
            float s = 0.f, q = 0.f;
            for (int t = 0; t < nbtIn; t += 4) {
                float4 a4 = *(const float4*)(ps + t);
                float4 b4 = *(const float4*)(pq + t);
                s += (a4.x + a4.y) + (a4.z + a4.w);
                q += (b4.x + b4.y) + (b4.z + b4.w);
            }
            const float mean = s * (1.f / BB);
            const float var  = q * (1.f / BB) - mean * mean;
            const float rstd = rsqrtf(var + 1e-5f);
            const float scv  = gIn[(size_t)c * K + f] * rstd;
            scs[f] = scv;
            shs[f] = fmaf(-mean, scv, beIn[(size_t)c * K + f]);
        }
        __syncthreads();
    }

    const int b0 = btile * BM, o0 = otile * 128;
    const int OT = Fout >> 7;
    const char* wbase = Wpk + (size_t)((c * OT + otile) * KS) * 16384;
    const char* abase = PREPACK ? (Apk + (size_t)((c * gridDim.x + btile) * KS) * 16384) : nullptr;

    const int lane = tid & 63, wv = tid >> 6;
    const int fr = lane & 15, fkc = lane >> 4;
    const int wrow = (BM == 128) ? ((wv >> 1) << 6) : ((wv >> 1) << 5);
    const int wcol = (wv & 1) << 6;
    const int wrg = wrow >> 4, wcg = wcol >> 4;
    constexpr int MI = BM / 32;

    f32x4 acc[MI][4];
    #pragma unroll
    for (int mi = 0; mi < MI; ++mi)
        #pragma unroll
        for (int ni = 0; ni < 4; ++ni)
            acc[mi][ni] = (f32x4){0.f, 0.f, 0.f, 0.f};

    if constexpr (PREPACK) {
        auto stageTile = [&](int nb, int ks) {
            const char* at = abase + (size_t)ks * 16384;
            const char* wt = wbase + (size_t)ks * 16384;
            char* dst = sm + nb;
            #pragma unroll
            for (int i = 0; i < 4; ++i) {
                const int rg = ((wv << 2) + i) << 10;
                gll16(at + rg + (lane << 4), dst + rg);
                gll16(wt + rg + (lane << 4), dst + 16384 + rg);
            }
        };
        stageTile(0, 0);
        __syncthreads();
        for (int ks = 0; ks < KS; ++ks) {
            const int cb = (ks & 1) ? BUFSZ : 0;
            if (ks + 1 < KS) stageTile(cb ^ BUFSZ, ks + 1);
            bf16x8 ah[MI], al[MI], wh[4], wl[4];
            #pragma unroll
            for (int i = 0; i < 4; ++i) {
                const int wo = ((wcg + i) << 10) | (fkc << 8) | (fr << 4);
                wh[i] = *(const bf16x8*)(sm + cb + 16384 + wo);
                wl[i] = *(const bf16x8*)(sm + cb + 24576 + wo);
            }
            #pragma unroll
            for (int i = 0; i < MI; ++i) {
                const int ao = ((wrg + i) << 10) | (fkc << 8) | (fr << 4);
                ah[i] = *(const bf16x8*)(sm + cb + ao);
                al[i] = *(const bf16x8*)(sm + cb + 8192 + ao);
            }
            #pragma unroll
            for (int mi = 0; mi < MI; ++mi)
                #pragma unroll
                for (int ni = 0; ni < 4; ++ni) {
                    acc[mi][ni] = __builtin_amdgcn_mfma_f32_16x16x32_bf16(ah[mi], wh[ni], acc[mi][ni], 0, 0, 0);
                    acc[mi][ni] = __builtin_amdgcn_mfma_f32_16x16x32_bf16(ah[mi], wl[ni], acc[mi][ni], 0, 0, 0);
                    acc[mi][ni] = __builtin_amdgcn_mfma_f32_16x16x32_bf16(al[mi], wh[ni], acc[mi][ni], 0, 0, 0);
                }
            __syncthreads();
        }
    } else {
        constexpr int NV = BM / 32;
        const int arow = (BM == 128) ? (tid >> 1) : (tid >> 2);
        const int asub = (BM == 128) ? (tid & 1)  : (tid & 3);
        const int ak0  = (BM == 128) ? (asub << 4) : (asub << 3);
        const int kch  = (BM == 128) ? (asub << 1) : asub;
        const int awr  = ((arow >> 4) << 10) | (kch << 8) | ((arow & 15) << 4);
        const float* Arow = A + ((size_t)c * BB + b0 + arow) * K;

        auto loadA = [&](float4 (&av)[NV], int gk0) {
            #pragma unroll
            for (int i = 0; i < NV; ++i)
                av[i] = *(const float4*)(Arow + gk0 + (i << 2));
        };
        auto loadW = [&](bf16x8 (&w)[8], int ks) {
            const char* wt = wbase + (size_t)ks * 16384;
            #pragma unroll
            for (int i = 0; i < 4; ++i) {
                const int wo = ((wcg + i) << 10) | (fkc << 8) | (fr << 4);
                w[i]     = *(const bf16x8*)(wt + wo);
                w[4 + i] = *(const bf16x8*)(wt + 8192 + wo);
            }
        };
        auto cvtStore = [&](char* dstbase, const float4 (&a)[NV], int gk0) {
            float e[NV * 4];
            #pragma unroll
            for (int i = 0; i < NV; ++i) {
                e[i*4+0] = a[i].x; e[i*4+1] = a[i].y; e[i*4+2] = a[i].z; e[i*4+3] = a[i].w;
            }
            if constexpr (FUSE_BN) {
                #pragma unroll
                for (int i = 0; i < NV; ++i) {
                    const float4 sc = *(const float4*)(scs + gk0 + (i << 2));
                    const float4 sh = *(const float4*)(shs + gk0 + (i << 2));
                    e[i*4+0] = fmaxf(0.f, fmaf(e[i*4+0], sc.x, sh.x));
                    e[i*4+1] = fmaxf(0.f, fmaf(e[i*4+1], sc.y, sh.y));
                    e[i*4+2] = fmaxf(0.f, fmaf(e[i*4+2], sc.z, sh.z));
                    e[i*4+3] = fmaxf(0.f, fmaf(e[i*4+3], sc.w, sh.w));
                }
            }
            short h[NV*4], l[NV*4];
            #pragma unroll
            for (int j = 0; j < NV*4; ++j) split2(e[j], h[j], l[j]);
            *(short8*)(dstbase + awr)         = (short8){h[0],h[1],h[2],h[3],h[4],h[5],h[6],h[7]};
            *(short8*)(dstbase + PLANE + awr) = (short8){l[0],l[1],l[2],l[3],l[4],l[5],l[6],l[7]};
            if constexpr (NV == 4) {
                *(short8*)(dstbase + awr + 256)         = (short8){h[8],h[9],h[10],h[11],h[12],h[13],h[14],h[15]};
                *(short8*)(dstbase + PLANE + awr + 256) = (short8){l[8],l[9],l[10],l[11],l[12],l[13],l[14],l[15]};
            }
        };
        auto rawStore = [&](char* dstbase, const float4 (&a)[NV]) {
            // ABL=1: identical ds_write pattern, zero convert VALU
            *(short8*)(dstbase + awr)         = __builtin_bit_cast(short8, a[0]);
            *(short8*)(dstbase + PLANE + awr) = __builtin_bit_cast(short8, a[NV > 1 ? 1 : 0]);
            if constexpr (NV == 4) {
                *(short8*)(dstbase + awr + 256)         = __builtin_bit_cast(short8, a[2]);
                *(short8*)(dstbase + PLANE + awr + 256) = __builtin_bit_cast(short8, a[3]);
            }
        };

        bf16x8 wcA[8], wcB[8];
        float4 avP[NV], avQ[NV];

        auto step = [&](int ks, char* cbp, char* nbp,
                        float4 (&avUse)[NV], float4 (&avLoad)[NV],
                        bf16x8 (&wUse)[8], bf16x8 (&wLoad)[8]) {
            const bool hn  = (ks + 1) < KS;
            const bool hn2 = (ks + 2) < KS;
            if constexpr (ABL != 2 && ABL != 5) {
                if (hn2) loadA(avLoad, ((ks + 2) << 5) + ak0);
            }
            if constexpr (ABL != 5) {
                if (hn) loadW(wLoad, ks + 1);
            }
            bf16x8 ah[MI], al[MI];
            #pragma unroll
            for (int i = 0; i < MI; ++i) {
                const int ao = ((wrg + i) << 10) | (fkc << 8) | (fr << 4);
                ah[i] = *(const bf16x8*)(cbp + ao);
                al[i] = *(const bf16x8*)(cbp + PLANE + ao);
            }
            #pragma unroll
            for (int mi = 0; mi < MI; ++mi)
                #pragma unroll
                for (int ni = 0; ni < 4; ++ni) {
                    acc[mi][ni] = __builtin_amdgcn_mfma_f32_16x16x32_bf16(ah[mi], wUse[ni],     acc[mi][ni], 0, 0, 0);
                    acc[mi][ni] = __builtin_amdgcn_mfma_f32_16x16x32_bf16(ah[mi], wUse[4 + ni], acc[mi][ni], 0, 0, 0);
                    acc[mi][ni] = __builtin_amdgcn_mfma_f32_16x16x32_bf16(al[mi], wUse[ni],     acc[mi][ni], 0, 0, 0);
                }
            if (hn) {
                if constexpr (ABL == 1)      rawStore(nbp, avUse);
                else if constexpr (ABL != 5) cvtStore(nbp, avUse, ((ks + 1) << 5) + ak0);
            }
            soft_barrier();
        };

        #pragma unroll 1
        for (int rep = 0; rep < REP; ++rep) {
            {
                float4 av0[NV];
                loadA(av0, ak0);
                loadW(wcA, 0);
                if (KS > 1) loadA(avP, 32 + ak0);
                if constexpr (ABL == 2) {
                    #pragma unroll
                    for (int i = 0; i < NV; ++i) avQ[i] = avP[i];
                }
                if constexpr (ABL == 5) {
                    #pragma unroll
                    for (int i = 0; i < 8; ++i) wcB[i] = wcA[i];
                }
                if constexpr (ABL == 1) rawStore(sm, av0);
                else                    cvtStore(sm, av0, ak0);
            }
            soft_barrier();

            for (int ks = 0; ks < KS; ks += 2) {
                step(ks,     sm,         sm + BUFSZ, avP, avQ, wcA, wcB);
                step(ks + 1, sm + BUFSZ, sm,         avQ, avP, wcB, wcA);
            }
        }
    }

    // ---- epilogue: bias, store, deterministic partial BN stats ----
    float bv[4];
    #pragma unroll
    for (int ni = 0; ni < 4; ++ni)
        bv[ni] = bias[(size_t)c * Fout + o0 + wcol + (ni << 4) + fr];

    float p[4] = {}, q[4] = {};
    const int rsub = (lane >> 4) << 2;
    #pragma unroll
    for (int mi = 0; mi < MI; ++mi) {
        #pragma unroll
        for (int j = 0; j < 4; ++j) {
            const int row = b0 + wrow + (mi << 4) + rsub + j;
            float* op = Out + ((size_t)c * BB + row) * Fout + o0 + wcol;
            #pragma unroll
            for (int ni = 0; ni < 4; ++ni) {
                const float v = acc[mi][ni][j] + bv[ni];
                op[(ni << 4) + fr] = v;
                if (WRITE_STATS) { p[ni] += v; q[ni] += v * v; }
            }
        }
    }

    if (WRITE_STATS) {
        #pragma unroll
        for (int ni = 0; ni < 4; ++ni) {
            p[ni] += __shfl_xor(p[ni], 16); p[ni] += __shfl_xor(p[ni], 32);
            q[ni] += __shfl_xor(q[ni], 16); q[ni] += __shfl_xor(q[ni], 32);
        }
        __syncthreads();
        float* redp = (float*)sm;
        float* redq = (float*)(sm + 1024);
        if (lane < 16) {
            const int base = (wv >> 1) * 128 + wcol;
            #pragma unroll
            for (int ni = 0; ni < 4; ++ni) {
                redp[base + (ni << 4) + fr] = p[ni];
                redq[base + (ni << 4) + fr] = q[ni];
            }
        }
        __syncthreads();
        if (tid < 128) {
            const float sp = redp[tid] + redp[128 + tid];
            const float sq = redq[tid] + redq[128 + tid];
            const size_t o = ((size_t)c * Fout + o0 + tid) * gridDim.x + btile;
            psumOut[o] = sp;
            psqOut[o]  = sq;
        }
    }
}

__global__ __launch_bounds__(256)
void label_kernel(float* __restrict__ out)
{
    const int i = blockIdx.x * 256 + threadIdx.x;
    out[i] = (float)(i >> 11);   // i / 2048
}

// ---------------------------------------------------------------------------
extern "C" void kernel_launch(void* const* d_in, const int* in_sizes, int n_in,
                              void* d_out, int out_size, void* d_ws, size_t ws_size,
                              hipStream_t stream)
{
    const float* x = (const float*)d_in[0];
    const float* W[5];  const float* bs[5];
    for (int l = 0; l < 5; ++l) { W[l] = (const float*)d_in[1 + 2 * l]; bs[l] = (const float*)d_in[2 + 2 * l]; }
    const float* g[4];  const float* be[4];
    for (int l = 0; l < 4; ++l) { g[l] = (const float*)d_in[11 + 2 * l]; be[l] = (const float*)d_in[12 + 2 * l]; }

    float* out     = (float*)d_out;
    float* gendata = out;                              // [C*BB, 512] — doubles as h1
    float* label   = out + (size_t)CCLS * BB * 512;

    float* ws  = (float*)d_ws;
    float* h2  = ws;                                   // 8,388,608 f (32MB)
    float* h3  = h2 + 8388608;                         // 4,194,304 f (16MB)
    float* h4  = h2;                                   // alias: h2 dead after G3
    float* ps1 = h3 + 4194304;
    float* pq1 = ps1 + 131072;
    float* ps2 = pq1 + 131072;
    float* pq2 = ps2 + 65536;
    float* ps3 = pq2 + 65536;
    float* pq3 = ps3 + 65536;
    float* ps4 = pq3 + 65536;
    float* pq4 = ps4 + 65536;
    char*  pack = (char*)(pq4 + 65536);                // 2560 x 16KB = 40MB

    const char* xpk  = pack;
    const char* wpk1 = pack + (size_t)1024 * 16384;
    const char* wpk2 = pack + (size_t)1280 * 16384;
    const char* wpk3 = pack + (size_t)1792 * 16384;
    const char* wpk4 = pack + (size_t)1920 * 16384;
    const char* wpk5 = pack + (size_t)2048 * 16384;

    const dim3 blk(256);

    PackDesc pd;
    pd.src[0] = x;    pd.src[1] = W[0]; pd.src[2] = W[1];
    pd.src[3] = W[2]; pd.src[4] = W[3]; pd.src[5] = W[4];
    const int nrt[6]   = {16, 4, 2, 1, 2, 4};
    const int ksn[6]   = {4, 4, 16, 8, 4, 8};
    const int kreal[6] = {100, 100, 512, 256, 128, 256};
    const int beg[7]   = {0, 1024, 1280, 1792, 1920, 2048, 2560};
    for (int i = 0; i < 6; ++i) { pd.nrt[i] = nrt[i]; pd.ksn[i] = ksn[i]; pd.kreal[i] = kreal[i]; }
    for (int i = 0; i < 7; ++i) pd.beg[i] = beg[i];
    pack_kernel<<<dim3(2560), blk, 0, stream>>>(pd, pack);

    // G1: x[K=100->128] -> h1(=gendata)[512], stats (PREPACK m97-style)
    gemm8_kernel<128, 128, true, false, true><<<dim3(16, 4, CCLS), blk, 0, stream>>>(
        nullptr, xpk, wpk1, bs[0], nullptr, nullptr, nullptr, nullptr,
        gendata, ps1, pq1, 512, 0);

    // G2: bn1(h1)->relu -> h2[256], stats
    gemm8_kernel<128, 512, false, true, true><<<dim3(16, 2, CCLS), blk, 0, stream>>>(
        gendata, nullptr, wpk2, bs[1], ps1, pq1, g[0], be[0],
        h2, ps2, pq2, 256, 16);

    // G3: bn2(h2)->relu -> h3[128], stats (BM=64)
    gemm8_kernel<64, 256, false, true, true><<<dim3(32, 1, CCLS), blk, 0, stream>>>(
        h2, nullptr, wpk3, bs[2], ps2, pq2, g[1], be[1],
        h3, ps3, pq3, 128, 16);

    // G4: bn3(h3)->relu -> h4[256] (aliases h2), stats
    gemm8_kernel<128, 128, false, true, true><<<dim3(16, 2, CCLS), blk, 0, stream>>>(
        h3, nullptr, wpk4, bs[3], ps3, pq3, g[2], be[2],
        h4, ps4, pq4, 256, 32);

    // G5: bn4(h4)->relu -> gendata[512] (no stats)
    gemm8_kernel<128, 256, false, true, false><<<dim3(16, 4, CCLS), blk, 0, stream>>>(
        h4, nullptr, wpk5, bs[4], ps4, pq4, g[3], be[3],
        gendata, nullptr, nullptr, 512, 16);

    label_kernel<<<dim3(CCLS * BB / 256), blk, 0, stream>>>(label);

    // ================= DIAGNOSTIC ABLATIONS (write only dead ws regions) ====
    // G2-shaped clones; input = gendata (final output values, deterministic),
    // BN params from layer-1 stats (alive). Out -> h2 (dead after G5),
    // stats -> ps3/pq3 (dead after G4). Identified in rocprof by adjacent
    // _ord (launched last, order D1 < D2 < D5) and duration band.
    // D1: no-convert staging (REP=2)  — isolates cvt VALU cost
    gemm8_kernel<128, 512, false, true, true, 1, 2><<<dim3(16, 2, CCLS), blk, 0, stream>>>(
        gendata, nullptr, wpk2, bs[1], ps1, pq1, g[0], be[0],
        h2, ps3, pq3, 256, 16);
    // D2: no in-loop A global loads (REP=2) — isolates A-load latency
    gemm8_kernel<128, 512, false, true, true, 2, 2><<<dim3(16, 2, CCLS), blk, 0, stream>>>(
        gendata, nullptr, wpk2, bs[1], ps1, pq1, g[0], be[0],
        h2, ps3, pq3, 256, 16);
    // D5: no staging at all (REP=3) — compute-skeleton floor
    gemm8_kernel<128, 512, false, true, true, 5, 3><<<dim3(16, 2, CCLS), blk, 0, stream>>>(
        gendata, nullptr, wpk2, bs[1], ps1, pq1, g[0], be[0],
        h2, ps3, pq3, 256, 16);
}

// Round 10
// 147.027 us; speedup vs baseline: 2.1898x; 2.1898x over previous
//
#include <hip/hip_runtime.h>
#include <hip/hip_bf16.h>
#include <math.h>

#define CCLS 16
#define BB   2048

using bf16x8 = __attribute__((ext_vector_type(8))) short;
using short8 = __attribute__((ext_vector_type(8))) short;
using f32x4  = __attribute__((ext_vector_type(4))) float;

// fp32 -> (hi, lo) bf16 split (RNE; hi+lo reproduces ~24 mantissa bits)
__device__ __forceinline__ void split2(float e, short& hi, short& lo) {
    __hip_bfloat16 h = __float2bfloat16(e);
    hi = __builtin_bit_cast(short, h);
    lo = __builtin_bit_cast(short, __float2bfloat16(e - __bfloat162float(h)));
}

// LDS-visibility barrier that does NOT drain vmcnt.
__device__ __forceinline__ void soft_barrier() {
    asm volatile("s_waitcnt lgkmcnt(0)" ::: "memory");
    __builtin_amdgcn_s_barrier();
    asm volatile("" ::: "memory");
}

// global -> LDS direct copy, 16B/lane; lds dest is wave-uniform base
__device__ __forceinline__ void gll16(const void* g, void* l) {
    __builtin_amdgcn_global_load_lds(
        (const __attribute__((address_space(1))) unsigned*)g,
        (__attribute__((address_space(3))) unsigned*)l, 16, 0, 0);
}

// Fragment-major layout for a 128-row x 32-k bf16 tile (8 KB/plane):
//   L(row, kchunk) = (row>>4)<<10 | kchunk<<8 | (row&15)<<4   (kchunk = k/8)

// ---------------------------------------------------------------------------
// One-time pack: x and W1..W5 -> [hi 8KB][lo 8KB] fragment-major 128x32 tiles.
// ---------------------------------------------------------------------------
struct PackDesc {
    const float* src[6];
    int nrt[6];
    int ksn[6];
    int kreal[6];
    int beg[7];
};

__global__ __launch_bounds__(256)
void pack_kernel(PackDesc d, char* __restrict__ base)
{
    const int bid = blockIdx.x;
    int s = 0;
    #pragma unroll
    for (int i = 0; i < 5; ++i) s += (bid >= d.beg[i + 1]);
    const int t    = bid - d.beg[s];
    const int ksn  = d.ksn[s], nrt = d.nrt[s], kreal = d.kreal[s];
    const int perc = nrt * ksn;
    const int c  = t / perc;
    const int r  = t - c * perc;
    const int rt = r / ksn;
    const int ks = r - rt * ksn;
    const float* src = d.src[s] + ((size_t)(c * nrt + rt) * 128) * kreal;
    char* dst = base + (size_t)bid * 16384;
    const int tid = threadIdx.x;

    #pragma unroll
    for (int it = 0; it < 2; ++it) {
        const int row = (tid >> 2) + (it << 6);
        const int cc  = tid & 3;
        const int q   = ((row >> 4) << 10) | (cc << 8) | ((row & 15) << 4);
        const int k0  = ks * 32 + cc * 8;
        const float* sp = src + (size_t)row * kreal + k0;
        float e[8];
        if (k0 + 8 <= kreal) {
            float4 v0 = *(const float4*)sp;
            float4 v1 = *(const float4*)(sp + 4);
            e[0]=v0.x; e[1]=v0.y; e[2]=v0.z; e[3]=v0.w;
            e[4]=v1.x; e[5]=v1.y; e[6]=v1.z; e[7]=v1.w;
        } else {
            #pragma unroll
            for (int j = 0; j < 8; ++j) e[j] = (k0 + j < kreal) ? sp[j] : 0.f;
        }
        short hv[8], lv[8];
        #pragma unroll
        for (int j = 0; j < 8; ++j) split2(e[j], hv[j], lv[j]);
        *(short8*)(dst + q)        = (short8){hv[0],hv[1],hv[2],hv[3],hv[4],hv[5],hv[6],hv[7]};
        *(short8*)(dst + 8192 + q) = (short8){lv[0],lv[1],lv[2],lv[3],lv[4],lv[5],lv[6],lv[7]};
    }
}

// ---------------------------------------------------------------------------
// 4-wave kernel (R8 structure): PREPACK path for G1, reg-staged path for G3.
// ---------------------------------------------------------------------------
template<int BM, int K, bool PREPACK, bool FUSE_BN, bool WRITE_STATS>
__global__ __launch_bounds__(256, 2)
void gemm4w_kernel(const float* __restrict__ A, const char* __restrict__ Apk,
                   const char* __restrict__ Wpk, const float* __restrict__ bias,
                   const float* __restrict__ psumIn, const float* __restrict__ psqIn,
                   const float* __restrict__ gIn, const float* __restrict__ beIn,
                   float* __restrict__ Out,
                   float* __restrict__ psumOut, float* __restrict__ psqOut,
                   const int Fout, const int nbtIn)
{
    constexpr int KS    = (K + 31) / 32;
    constexpr int PLANE = BM * 64;
    constexpr int BUFSZ = PREPACK ? 32768 : 2 * PLANE;
    static_assert(PREPACK || (K % 32 == 0), "");
    static_assert(PREPACK || (KS % 2 == 0) || (KS == 1), "");

    __shared__ __align__(16) char sm[2 * BUFSZ + (FUSE_BN ? 8 * K : 16)];
    float* scs = (float*)(sm + 2 * BUFSZ);
    float* shs = scs + (FUSE_BN ? K : 0);

    const int tid   = threadIdx.x;
    const int btile = blockIdx.x, otile = blockIdx.y, c = blockIdx.z;

    if (FUSE_BN) {
        for (int f = tid; f < K; f += 256) {
            const float* ps = psumIn + ((size_t)c * K + f) * nbtIn;
            const float* pq = psqIn  + ((size_t)c * K + f) * nbtIn;
            float s = 0.f, q = 0.f;
            for (int t = 0; t < nbtIn; t += 4) {
                float4 a4 = *(const float4*)(ps + t);
                float4 b4 = *(const float4*)(pq + t);
                s += (a4.x + a4.y) + (a4.z + a4.w);
                q += (b4.x + b4.y) + (b4.z + b4.w);
            }
            const float mean = s * (1.f / BB);
            const float var  = q * (1.f / BB) - mean * mean;
            const float rstd = rsqrtf(var + 1e-5f);
            const float scv  = gIn[(size_t)c * K + f] * rstd;
            scs[f] = scv;
            shs[f] = fmaf(-mean, scv, beIn[(size_t)c * K + f]);
        }
        __syncthreads();
    }

    const int b0 = btile * BM, o0 = otile * 128;
    const int OT = Fout >> 7;
    const char* wbase = Wpk + (size_t)((c * OT + otile) * KS) * 16384;
    const char* abase = PREPACK ? (Apk + (size_t)((c * gridDim.x + btile) * KS) * 16384) : nullptr;

    const int lane = tid & 63, wv = tid >> 6;
    const int fr = lane & 15, fkc = lane >> 4;
    const int wrow = (BM == 128) ? ((wv >> 1) << 6) : ((wv >> 1) << 5);
    const int wcol = (wv & 1) << 6;
    const int wrg = wrow >> 4, wcg = wcol >> 4;
    constexpr int MI = BM / 32;

    f32x4 acc[MI][4];
    #pragma unroll
    for (int mi = 0; mi < MI; ++mi)
        #pragma unroll
        for (int ni = 0; ni < 4; ++ni)
            acc[mi][ni] = (f32x4){0.f, 0.f, 0.f, 0.f};

    if constexpr (PREPACK) {
        auto stageTile = [&](int nb, int ks) {
            const char* at = abase + (size_t)ks * 16384;
            const char* wt = wbase + (size_t)ks * 16384;
            char* dst = sm + nb;
            #pragma unroll
            for (int i = 0; i < 4; ++i) {
                const int rg = ((wv << 2) + i) << 10;
                gll16(at + rg + (lane << 4), dst + rg);
                gll16(wt + rg + (lane << 4), dst + 16384 + rg);
            }
        };
        stageTile(0, 0);
        __syncthreads();
        for (int ks = 0; ks < KS; ++ks) {
            const int cb = (ks & 1) ? BUFSZ : 0;
            if (ks + 1 < KS) stageTile(cb ^ BUFSZ, ks + 1);
            bf16x8 ah[MI], al[MI], wh[4], wl[4];
            #pragma unroll
            for (int i = 0; i < 4; ++i) {
                const int wo = ((wcg + i) << 10) | (fkc << 8) | (fr << 4);
                wh[i] = *(const bf16x8*)(sm + cb + 16384 + wo);
                wl[i] = *(const bf16x8*)(sm + cb + 24576 + wo);
            }
            #pragma unroll
            for (int i = 0; i < MI; ++i) {
                const int ao = ((wrg + i) << 10) | (fkc << 8) | (fr << 4);
                ah[i] = *(const bf16x8*)(sm + cb + ao);
                al[i] = *(const bf16x8*)(sm + cb + 8192 + ao);
            }
            #pragma unroll
            for (int mi = 0; mi < MI; ++mi)
                #pragma unroll
                for (int ni = 0; ni < 4; ++ni) {
                    acc[mi][ni] = __builtin_amdgcn_mfma_f32_16x16x32_bf16(ah[mi], wh[ni], acc[mi][ni], 0, 0, 0);
                    acc[mi][ni] = __builtin_amdgcn_mfma_f32_16x16x32_bf16(ah[mi], wl[ni], acc[mi][ni], 0, 0, 0);
                    acc[mi][ni] = __builtin_amdgcn_mfma_f32_16x16x32_bf16(al[mi], wh[ni], acc[mi][ni], 0, 0, 0);
                }
            __syncthreads();
        }
    } else {
        constexpr int NV = BM / 32;
        const int arow = (BM == 128) ? (tid >> 1) : (tid >> 2);
        const int asub = (BM == 128) ? (tid & 1)  : (tid & 3);
        const int ak0  = (BM == 128) ? (asub << 4) : (asub << 3);
        const int kch  = (BM == 128) ? (asub << 1) : asub;
        const int awr  = ((arow >> 4) << 10) | (kch << 8) | ((arow & 15) << 4);
        const float* Arow = A + ((size_t)c * BB + b0 + arow) * K;

        auto loadA = [&](float4 (&av)[NV], int gk0) {
            #pragma unroll
            for (int i = 0; i < NV; ++i)
                av[i] = *(const float4*)(Arow + gk0 + (i << 2));
        };
        auto loadW = [&](bf16x8 (&w)[8], int ks) {
            const char* wt = wbase + (size_t)ks * 16384;
            #pragma unroll
            for (int i = 0; i < 4; ++i) {
                const int wo = ((wcg + i) << 10) | (fkc << 8) | (fr << 4);
                w[i]     = *(const bf16x8*)(wt + wo);
                w[4 + i] = *(const bf16x8*)(wt + 8192 + wo);
            }
        };
        auto cvtStore = [&](char* dstbase, const float4 (&a)[NV], int gk0) {
            float e[NV * 4];
            #pragma unroll
            for (int i = 0; i < NV; ++i) {
                e[i*4+0] = a[i].x; e[i*4+1] = a[i].y; e[i*4+2] = a[i].z; e[i*4+3] = a[i].w;
            }
            if constexpr (FUSE_BN) {
                #pragma unroll
                for (int i = 0; i < NV; ++i) {
                    const float4 sc = *(const float4*)(scs + gk0 + (i << 2));
                    const float4 sh = *(const float4*)(shs + gk0 + (i << 2));
                    e[i*4+0] = fmaxf(0.f, fmaf(e[i*4+0], sc.x, sh.x));
                    e[i*4+1] = fmaxf(0.f, fmaf(e[i*4+1], sc.y, sh.y));
                    e[i*4+2] = fmaxf(0.f, fmaf(e[i*4+2], sc.z, sh.z));
                    e[i*4+3] = fmaxf(0.f, fmaf(e[i*4+3], sc.w, sh.w));
                }
            }
            short h[NV*4], l[NV*4];
            #pragma unroll
            for (int j = 0; j < NV*4; ++j) split2(e[j], h[j], l[j]);
            *(short8*)(dstbase + awr)         = (short8){h[0],h[1],h[2],h[3],h[4],h[5],h[6],h[7]};
            *(short8*)(dstbase + PLANE + awr) = (short8){l[0],l[1],l[2],l[3],l[4],l[5],l[6],l[7]};
            if constexpr (NV == 4) {
                *(short8*)(dstbase + awr + 256)         = (short8){h[8],h[9],h[10],h[11],h[12],h[13],h[14],h[15]};
                *(short8*)(dstbase + PLANE + awr + 256) = (short8){l[8],l[9],l[10],l[11],l[12],l[13],l[14],l[15]};
            }
        };

        bf16x8 wcA[8], wcB[8];
        float4 avP[NV], avQ[NV];

        auto step = [&](int ks, char* cbp, char* nbp,
                        float4 (&avUse)[NV], float4 (&avLoad)[NV],
                        bf16x8 (&wUse)[8], bf16x8 (&wLoad)[8]) {
            const bool hn  = (ks + 1) < KS;
            const bool hn2 = (ks + 2) < KS;
            if (hn2) loadA(avLoad, ((ks + 2) << 5) + ak0);
            if (hn)  loadW(wLoad, ks + 1);
            bf16x8 ah[MI], al[MI];
            #pragma unroll
            for (int i = 0; i < MI; ++i) {
                const int ao = ((wrg + i) << 10) | (fkc << 8) | (fr << 4);
                ah[i] = *(const bf16x8*)(cbp + ao);
                al[i] = *(const bf16x8*)(cbp + PLANE + ao);
            }
            #pragma unroll
            for (int mi = 0; mi < MI; ++mi)
                #pragma unroll
                for (int ni = 0; ni < 4; ++ni) {
                    acc[mi][ni] = __builtin_amdgcn_mfma_f32_16x16x32_bf16(ah[mi], wUse[ni],     acc[mi][ni], 0, 0, 0);
                    acc[mi][ni] = __builtin_amdgcn_mfma_f32_16x16x32_bf16(ah[mi], wUse[4 + ni], acc[mi][ni], 0, 0, 0);
                    acc[mi][ni] = __builtin_amdgcn_mfma_f32_16x16x32_bf16(al[mi], wUse[ni],     acc[mi][ni], 0, 0, 0);
                }
            if (hn) cvtStore(nbp, avUse, ((ks + 1) << 5) + ak0);
            soft_barrier();
        };

        {
            float4 av0[NV];
            loadA(av0, ak0);
            loadW(wcA, 0);
            if (KS > 1) loadA(avP, 32 + ak0);
            cvtStore(sm, av0, ak0);
        }
        soft_barrier();

        for (int ks = 0; ks < KS; ks += 2) {
            step(ks,     sm,         sm + BUFSZ, avP, avQ, wcA, wcB);
            step(ks + 1, sm + BUFSZ, sm,         avQ, avP, wcB, wcA);
        }
    }

    // ---- epilogue: bias, store, deterministic partial BN stats ----
    float bv[4];
    #pragma unroll
    for (int ni = 0; ni < 4; ++ni)
        bv[ni] = bias[(size_t)c * Fout + o0 + wcol + (ni << 4) + fr];

    float p[4] = {}, q[4] = {};
    const int rsub = (lane >> 4) << 2;
    #pragma unroll
    for (int mi = 0; mi < MI; ++mi) {
        #pragma unroll
        for (int j = 0; j < 4; ++j) {
            const int row = b0 + wrow + (mi << 4) + rsub + j;
            float* op = Out + ((size_t)c * BB + row) * Fout + o0 + wcol;
            #pragma unroll
            for (int ni = 0; ni < 4; ++ni) {
                const float v = acc[mi][ni][j] + bv[ni];
                op[(ni << 4) + fr] = v;
                if (WRITE_STATS) { p[ni] += v; q[ni] += v * v; }
            }
        }
    }

    if (WRITE_STATS) {
        #pragma unroll
        for (int ni = 0; ni < 4; ++ni) {
            p[ni] += __shfl_xor(p[ni], 16); p[ni] += __shfl_xor(p[ni], 32);
            q[ni] += __shfl_xor(q[ni], 16); q[ni] += __shfl_xor(q[ni], 32);
        }
        __syncthreads();
        float* redp = (float*)sm;
        float* redq = (float*)(sm + 1024);
        if (lane < 16) {
            const int base = (wv >> 1) * 128 + wcol;
            #pragma unroll
            for (int ni = 0; ni < 4; ++ni) {
                redp[base + (ni << 4) + fr] = p[ni];
                redq[base + (ni << 4) + fr] = q[ni];
            }
        }
        __syncthreads();
        if (tid < 128) {
            const float sp = redp[tid] + redp[128 + tid];
            const float sq = redq[tid] + redq[128 + tid];
            const size_t o = ((size_t)c * Fout + o0 + tid) * gridDim.x + btile;
            psumOut[o] = sp;
            psqOut[o]  = sq;
        }
    }
}

// ---------------------------------------------------------------------------
// 8-wave (512-thread) 128x256 tile kernel: same per-wave structure as the
// 4-wave reg-staged path (64x64 per wave, W reg-dbuf, 2-deep A prefetch,
// soft barrier), but one block covers 256 output cols -> each A element is
// BN+ReLU+split-converted ONCE (OT-redundancy removed: the D1-measured 27%).
// Waves arranged 2(M) x 4(N). Always FUSE_BN.
// ---------------------------------------------------------------------------
template<int K, bool WRITE_STATS>
__global__ __launch_bounds__(512, 2)
void gemm8w_kernel(const float* __restrict__ A, const char* __restrict__ Wpk,
                   const float* __restrict__ bias,
                   const float* __restrict__ psumIn, const float* __restrict__ psqIn,
                   const float* __restrict__ gIn, const float* __restrict__ beIn,
                   float* __restrict__ Out,
                   float* __restrict__ psumOut, float* __restrict__ psqOut,
                   const int Fout, const int nbtIn)
{
    constexpr int KS    = K / 32;
    constexpr int PLANE = 8192;     // 128x32 bf16 plane
    constexpr int BUFSZ = 16384;    // hi+lo
    static_assert(K % 32 == 0 && (KS % 2 == 0), "");

    __shared__ __align__(16) char sm[2 * BUFSZ + 8 * K];
    float* scs = (float*)(sm + 2 * BUFSZ);
    float* shs = scs + K;

    const int tid   = threadIdx.x;
    const int btile = blockIdx.x, otile = blockIdx.y, c = blockIdx.z;

    // folded combine: BN scale/shift for INPUT features
    for (int f = tid; f < K; f += 512) {
        const float* ps = psumIn + ((size_t)c * K + f) * nbtIn;
        const float* pq = psqIn  + ((size_t)c * K + f) * nbtIn;
        float s = 0.f, q = 0.f;
        for (int t = 0; t < nbtIn; t += 4) {
            float4 a4 = *(const float4*)(ps + t);
            float4 b4 = *(const float4*)(pq + t);
            s += (a4.x + a4.y) + (a4.z + a4.w);
            q += (b4.x + b4.y) + (b4.z + b4.w);
        }
        const float mean = s * (1.f / BB);
        const float var  = q * (1.f / BB) - mean * mean;
        const float rstd = rsqrtf(var + 1e-5f);
        const float scv  = gIn[(size_t)c * K + f] * rstd;
        scs[f] = scv;
        shs[f] = fmaf(-mean, scv, beIn[(size_t)c * K + f]);
    }
    __syncthreads();

    const int b0 = btile * 128, o0 = otile * 256;
    const int OT128 = Fout >> 7;

    // A staging map: 512 threads, 8 floats each (one 16B frag slot)
    const int arow = tid >> 2, asub = tid & 3;
    const int ak0  = asub << 3;
    const int awr  = ((arow >> 4) << 10) | (asub << 8) | ((arow & 15) << 4);
    const float* Arow = A + ((size_t)c * BB + b0 + arow) * K;

    // wave map: 2(M) x 4(N), each wave 64x64
    const int lane = tid & 63, wv = tid >> 6;
    const int wr = wv >> 2, nc = wv & 3;
    const int wrow = wr << 6, wcol = nc << 6;
    const int fr = lane & 15, fkc = lane >> 4;
    const int wrg = wrow >> 4;
    const int wtile = wcol >> 7;            // which packed 128-col tile (0/1)
    const int wcg = (wcol >> 4) & 7;        // 16-col group within that tile
    const char* wbase = Wpk + (size_t)((c * OT128 + otile * 2 + wtile) * KS) * 16384;

    auto loadA = [&](float4 (&av)[2], int gk0) {
        av[0] = *(const float4*)(Arow + gk0);
        av[1] = *(const float4*)(Arow + gk0 + 4);
    };
    auto loadW = [&](bf16x8 (&w)[8], int ks) {
        const char* wt = wbase + (size_t)ks * 16384;
        #pragma unroll
        for (int i = 0; i < 4; ++i) {
            const int wo = ((wcg + i) << 10) | (fkc << 8) | (fr << 4);
            w[i]     = *(const bf16x8*)(wt + wo);
            w[4 + i] = *(const bf16x8*)(wt + 8192 + wo);
        }
    };
    auto cvtStore = [&](char* dstbase, const float4 (&a)[2], int gk0) {
        float e[8] = {a[0].x, a[0].y, a[0].z, a[0].w, a[1].x, a[1].y, a[1].z, a[1].w};
        const float4 sc0 = *(const float4*)(scs + gk0);
        const float4 sc1 = *(const float4*)(scs + gk0 + 4);
        const float4 sh0 = *(const float4*)(shs + gk0);
        const float4 sh1 = *(const float4*)(shs + gk0 + 4);
        e[0] = fmaxf(0.f, fmaf(e[0], sc0.x, sh0.x));
        e[1] = fmaxf(0.f, fmaf(e[1], sc0.y, sh0.y));
        e[2] = fmaxf(0.f, fmaf(e[2], sc0.z, sh0.z));
        e[3] = fmaxf(0.f, fmaf(e[3], sc0.w, sh0.w));
        e[4] = fmaxf(0.f, fmaf(e[4], sc1.x, sh1.x));
        e[5] = fmaxf(0.f, fmaf(e[5], sc1.y, sh1.y));
        e[6] = fmaxf(0.f, fmaf(e[6], sc1.z, sh1.z));
        e[7] = fmaxf(0.f, fmaf(e[7], sc1.w, sh1.w));
        short h[8], l[8];
        #pragma unroll
        for (int j = 0; j < 8; ++j) split2(e[j], h[j], l[j]);
        *(short8*)(dstbase + awr)         = (short8){h[0],h[1],h[2],h[3],h[4],h[5],h[6],h[7]};
        *(short8*)(dstbase + PLANE + awr) = (short8){l[0],l[1],l[2],l[3],l[4],l[5],l[6],l[7]};
    };

    f32x4 acc[4][4];
    #pragma unroll
    for (int mi = 0; mi < 4; ++mi)
        #pragma unroll
        for (int ni = 0; ni < 4; ++ni)
            acc[mi][ni] = (f32x4){0.f, 0.f, 0.f, 0.f};

    bf16x8 wcA[8], wcB[8];
    float4 avP[2], avQ[2];

    auto step = [&](int ks, char* cbp, char* nbp,
                    float4 (&avUse)[2], float4 (&avLoad)[2],
                    bf16x8 (&wUse)[8], bf16x8 (&wLoad)[8]) {
        const bool hn  = (ks + 1) < KS;
        const bool hn2 = (ks + 2) < KS;
        if (hn2) loadA(avLoad, ((ks + 2) << 5) + ak0);
        if (hn)  loadW(wLoad, ks + 1);
        bf16x8 ah[4], al[4];
        #pragma unroll
        for (int i = 0; i < 4; ++i) {
            const int ao = ((wrg + i) << 10) | (fkc << 8) | (fr << 4);
            ah[i] = *(const bf16x8*)(cbp + ao);
            al[i] = *(const bf16x8*)(cbp + PLANE + ao);
        }
        #pragma unroll
        for (int mi = 0; mi < 4; ++mi)
            #pragma unroll
            for (int ni = 0; ni < 4; ++ni) {
                acc[mi][ni] = __builtin_amdgcn_mfma_f32_16x16x32_bf16(ah[mi], wUse[ni],     acc[mi][ni], 0, 0, 0);
                acc[mi][ni] = __builtin_amdgcn_mfma_f32_16x16x32_bf16(ah[mi], wUse[4 + ni], acc[mi][ni], 0, 0, 0);
                acc[mi][ni] = __builtin_amdgcn_mfma_f32_16x16x32_bf16(al[mi], wUse[ni],     acc[mi][ni], 0, 0, 0);
            }
        if (hn) cvtStore(nbp, avUse, ((ks + 1) << 5) + ak0);
        soft_barrier();
    };

    {
        float4 av0[2];
        loadA(av0, ak0);
        loadW(wcA, 0);
        loadA(avP, 32 + ak0);
        cvtStore(sm, av0, ak0);
    }
    soft_barrier();

    for (int ks = 0; ks < KS; ks += 2) {
        step(ks,     sm,         sm + BUFSZ, avP, avQ, wcA, wcB);
        step(ks + 1, sm + BUFSZ, sm,         avQ, avP, wcB, wcA);
    }

    // ---- epilogue: bias, store, deterministic partial BN stats ----
    // C/D layout: col = lane&15, row = (lane>>4)*4 + reg
    float bv[4];
    #pragma unroll
    for (int ni = 0; ni < 4; ++ni)
        bv[ni] = bias[(size_t)c * Fout + o0 + wcol + (ni << 4) + fr];

    float p[4] = {}, q[4] = {};
    const int rsub = (lane >> 4) << 2;
    #pragma unroll
    for (int mi = 0; mi < 4; ++mi) {
        #pragma unroll
        for (int j = 0; j < 4; ++j) {
            const int row = b0 + wrow + (mi << 4) + rsub + j;
            float* op = Out + ((size_t)c * BB + row) * Fout + o0 + wcol;
            #pragma unroll
            for (int ni = 0; ni < 4; ++ni) {
                const float v = acc[mi][ni][j] + bv[ni];
                op[(ni << 4) + fr] = v;
                if (WRITE_STATS) { p[ni] += v; q[ni] += v * v; }
            }
        }
    }

    if (WRITE_STATS) {
        #pragma unroll
        for (int ni = 0; ni < 4; ++ni) {
            p[ni] += __shfl_xor(p[ni], 16); p[ni] += __shfl_xor(p[ni], 32);
            q[ni] += __shfl_xor(q[ni], 16); q[ni] += __shfl_xor(q[ni], 32);
        }
        __syncthreads();                    // loop done; reuse sm as scratch
        float* redp = (float*)sm;           // [2][256]
        float* redq = (float*)(sm + 2048);
        if (lane < 16) {
            const int base = wr * 256 + wcol;
            #pragma unroll
            for (int ni = 0; ni < 4; ++ni) {
                redp[base + (ni << 4) + fr] = p[ni];
                redq[base + (ni << 4) + fr] = q[ni];
            }
        }
        __syncthreads();
        if (tid < 256) {
            const float sp = redp[tid] + redp[256 + tid];
            const float sq = redq[tid] + redq[256 + tid];
            const size_t o = ((size_t)c * Fout + o0 + tid) * gridDim.x + btile;
            psumOut[o] = sp;
            psqOut[o]  = sq;
        }
    }
}

__global__ __launch_bounds__(256)
void label_kernel(float* __restrict__ out)
{
    const int i = blockIdx.x * 256 + threadIdx.x;
    out[i] = (float)(i >> 11);   // i / 2048
}

// ---------------------------------------------------------------------------
extern "C" void kernel_launch(void* const* d_in, const int* in_sizes, int n_in,
                              void* d_out, int out_size, void* d_ws, size_t ws_size,
                              hipStream_t stream)
{
    const float* x = (const float*)d_in[0];
    const float* W[5];  const float* bs[5];
    for (int l = 0; l < 5; ++l) { W[l] = (const float*)d_in[1 + 2 * l]; bs[l] = (const float*)d_in[2 + 2 * l]; }
    const float* g[4];  const float* be[4];
    for (int l = 0; l < 4; ++l) { g[l] = (const float*)d_in[11 + 2 * l]; be[l] = (const float*)d_in[12 + 2 * l]; }

    float* out     = (float*)d_out;
    float* gendata = out;                              // [C*BB, 512] — doubles as h1
    float* label   = out + (size_t)CCLS * BB * 512;

    float* ws  = (float*)d_ws;
    float* h2  = ws;                                   // 32MB
    float* h3  = h2 + 8388608;                         // 16MB
    float* h4  = h2;                                   // alias: h2 dead after G3
    float* ps1 = h3 + 4194304;
    float* pq1 = ps1 + 131072;
    float* ps2 = pq1 + 131072;
    float* pq2 = ps2 + 65536;
    float* ps3 = pq2 + 65536;
    float* pq3 = ps3 + 65536;
    float* ps4 = pq3 + 65536;
    float* pq4 = ps4 + 65536;
    char*  pack = (char*)(pq4 + 65536);                // 2560 x 16KB = 40MB

    const char* xpk  = pack;
    const char* wpk1 = pack + (size_t)1024 * 16384;
    const char* wpk2 = pack + (size_t)1280 * 16384;
    const char* wpk3 = pack + (size_t)1792 * 16384;
    const char* wpk4 = pack + (size_t)1920 * 16384;
    const char* wpk5 = pack + (size_t)2048 * 16384;

    const dim3 blk(256);

    PackDesc pd;
    pd.src[0] = x;    pd.src[1] = W[0]; pd.src[2] = W[1];
    pd.src[3] = W[2]; pd.src[4] = W[3]; pd.src[5] = W[4];
    const int nrt[6]   = {16, 4, 2, 1, 2, 4};
    const int ksn[6]   = {4, 4, 16, 8, 4, 8};
    const int kreal[6] = {100, 100, 512, 256, 128, 256};
    const int beg[7]   = {0, 1024, 1280, 1792, 1920, 2048, 2560};
    for (int i = 0; i < 6; ++i) { pd.nrt[i] = nrt[i]; pd.ksn[i] = ksn[i]; pd.kreal[i] = kreal[i]; }
    for (int i = 0; i < 7; ++i) pd.beg[i] = beg[i];
    pack_kernel<<<dim3(2560), blk, 0, stream>>>(pd, pack);

    // G1: x[K=100->128] -> h1(=gendata)[512], stats -> ps1 (nbt=16)
    gemm4w_kernel<128, 128, true, false, true><<<dim3(16, 4, CCLS), blk, 0, stream>>>(
        nullptr, xpk, wpk1, bs[0], nullptr, nullptr, nullptr, nullptr,
        gendata, ps1, pq1, 512, 0);

    // G2: bn1(h1)->relu -> h2[256], stats -> ps2 (nbt=16). 8-wave, OT=1.
    gemm8w_kernel<512, true><<<dim3(16, 1, CCLS), dim3(512), 0, stream>>>(
        gendata, wpk2, bs[1], ps1, pq1, g[0], be[0],
        h2, ps2, pq2, 256, 16);

    // G3: bn2(h2)->relu -> h3[128], stats -> ps3 (BM=64, nbt=32)
    gemm4w_kernel<64, 256, false, true, true><<<dim3(32, 1, CCLS), blk, 0, stream>>>(
        h2, nullptr, wpk3, bs[2], ps2, pq2, g[1], be[1],
        h3, ps3, pq3, 128, 16);

    // G4: bn3(h3)->relu -> h4[256] (aliases h2), stats -> ps4 (nbt=16). 8-wave.
    gemm8w_kernel<128, true><<<dim3(16, 1, CCLS), dim3(512), 0, stream>>>(
        h3, wpk4, bs[3], ps3, pq3, g[2], be[2],
        h4, ps4, pq4, 256, 32);

    // G5: bn4(h4)->relu -> gendata[512] (no stats). 8-wave, OT=2.
    gemm8w_kernel<256, false><<<dim3(16, 2, CCLS), dim3(512), 0, stream>>>(
        h4, wpk5, bs[4], ps4, pq4, g[3], be[3],
        gendata, nullptr, nullptr, 512, 16);

    label_kernel<<<dim3(CCLS * BB / 256), blk, 0, stream>>>(label);
}